// Round 5
// baseline (172.489 us; speedup 1.0000x reference)
//
#include <hip/hip_runtime.h>

#define HD 8
#define CD 16
#define DIM 128
#define NEG_SLOPE 0.2f

static __device__ __forceinline__ float lrelu(float v){ return v > 0.f ? v : NEG_SLOPE*v; }

// ---------------- K1: h = x @ W, plus alpha_src/alpha_dst epilogue ----------------
__global__ __launch_bounds__(256) void k_gemm(const float* __restrict__ x,
    const float* __restrict__ W, const float* __restrict__ a_src_g, const float* __restrict__ a_dst_g,
    float* __restrict__ hout, float* __restrict__ as_o, float* __restrict__ ad_o, int N)
{
  __shared__ float xs[64*DIM]; // 32 KB
  const int tid = threadIdx.x;
  const int c = tid & 31;
  const int r = tid >> 5;
  const long nbase = (long)blockIdx.x * 64;

  #pragma unroll
  for (int it = 0; it < 8; ++it){
    int lin = it*1024 + tid*4;
    long node = nbase + (lin >> 7);
    float4 v = make_float4(0.f,0.f,0.f,0.f);
    if (node < N) v = *(const float4*)(x + node*DIM + (lin & 127));
    *(float4*)(xs + lin) = v;
  }
  __syncthreads();

  float acc[8][4];
  #pragma unroll
  for (int i = 0; i < 8; ++i){ acc[i][0]=0.f; acc[i][1]=0.f; acc[i][2]=0.f; acc[i][3]=0.f; }

  for (int k = 0; k < DIM; k += 4){
    float4 w0 = *(const float4*)(W + (size_t)(k+0)*DIM + 4*c);
    float4 w1 = *(const float4*)(W + (size_t)(k+1)*DIM + 4*c);
    float4 w2 = *(const float4*)(W + (size_t)(k+2)*DIM + 4*c);
    float4 w3 = *(const float4*)(W + (size_t)(k+3)*DIM + 4*c);
    #pragma unroll
    for (int i = 0; i < 8; ++i){
      float4 xv = *(const float4*)(xs + (r*8+i)*DIM + k);
      acc[i][0] += xv.x*w0.x + xv.y*w1.x + xv.z*w2.x + xv.w*w3.x;
      acc[i][1] += xv.x*w0.y + xv.y*w1.y + xv.z*w2.y + xv.w*w3.y;
      acc[i][2] += xv.x*w0.z + xv.y*w1.z + xv.z*w2.z + xv.w*w3.z;
      acc[i][3] += xv.x*w0.w + xv.y*w1.w + xv.z*w2.w + xv.w*w3.w;
    }
  }

  float4 asv = *(const float4*)(a_src_g + 4*c);
  float4 adv = *(const float4*)(a_dst_g + 4*c);
  #pragma unroll
  for (int i = 0; i < 8; ++i){
    long node = nbase + r*8 + i;
    float ps = acc[i][0]*asv.x + acc[i][1]*asv.y + acc[i][2]*asv.z + acc[i][3]*asv.w;
    float pd = acc[i][0]*adv.x + acc[i][1]*adv.y + acc[i][2]*adv.z + acc[i][3]*adv.w;
    ps += __shfl_xor(ps, 1); ps += __shfl_xor(ps, 2);
    pd += __shfl_xor(pd, 1); pd += __shfl_xor(pd, 2);
    if (node < N){
      *(float4*)(hout + node*DIM + 4*c) = make_float4(acc[i][0],acc[i][1],acc[i][2],acc[i][3]);
      if ((c & 3) == 0){
        as_o[node*HD + (c>>2)] = ps;
        ad_o[node*HD + (c>>2)] = pd;
      }
    }
  }
}

// ---------------- CSR build ----------------
__global__ void k_count(const int* __restrict__ dst, int* __restrict__ cnt, int E){
  int e = blockIdx.x*256 + threadIdx.x;
  if (e < E) atomicAdd(&cnt[dst[e]], 1);
}

__global__ __launch_bounds__(256) void k_scan1(const int* __restrict__ cnt, int* __restrict__ bsum,
                                               int chunk, int N){
  __shared__ int tmp[256];
  int t = threadIdx.x;
  int base = blockIdx.x * chunk;
  int i = base + t;
  int v = (t < chunk && i < N) ? cnt[i] : 0;
  tmp[t] = v; __syncthreads();
  for (int off = 128; off > 0; off >>= 1){
    if (t < off) tmp[t] += tmp[t+off];
    __syncthreads();
  }
  if (t == 0) bsum[blockIdx.x] = tmp[0];
}

__global__ __launch_bounds__(256) void k_scan2(int* __restrict__ bsum, int* __restrict__ row_ofs, int N){
  __shared__ int tmp[256];
  int t = threadIdx.x;
  int v = bsum[t];
  tmp[t] = v; __syncthreads();
  for (int off = 1; off < 256; off <<= 1){
    int u = (t >= off) ? tmp[t-off] : 0;
    __syncthreads();
    tmp[t] += u;
    __syncthreads();
  }
  bsum[t] = tmp[t] - v;            // exclusive
  if (t == 255) row_ofs[N] = tmp[255];
}

__global__ __launch_bounds__(256) void k_scan3(const int* __restrict__ cnt, const int* __restrict__ bsum,
                                               int* __restrict__ row_ofs, int* __restrict__ wpos,
                                               int chunk, int N){
  __shared__ int tmp[256];
  int t = threadIdx.x;
  int base = blockIdx.x * chunk;
  int i = base + t;
  int v = (t < chunk && i < N) ? cnt[i] : 0;
  tmp[t] = v; __syncthreads();
  for (int off = 1; off < 256; off <<= 1){
    int u = (t >= off) ? tmp[t-off] : 0;
    __syncthreads();
    tmp[t] += u;
    __syncthreads();
  }
  int excl = tmp[t] - v;
  int bbase = bsum[blockIdx.x];
  if (t < chunk && i < N){
    row_ofs[i] = bbase + excl;
    wpos[i]    = bbase + excl;
  }
}

// scatter edges into CSR order; compute FINAL per-edge softmax weights (post-exp)
// for all 8 heads once per edge (valid because no max-shift is needed).
__global__ void k_scatter(const int* __restrict__ src, const int* __restrict__ dst,
                          const float* __restrict__ as_, const float* __restrict__ ad_,
                          int* __restrict__ wpos, int* __restrict__ csr_src,
                          float* __restrict__ w_csr, int E){
  int e = blockIdx.x*256 + threadIdx.x;
  if (e >= E) return;
  int s = src[e], d = dst[e];
  int pos = atomicAdd(&wpos[d], 1);
  csr_src[pos] = s;
  float4 s0 = *(const float4*)(as_ + (size_t)s*HD);
  float4 s1 = *(const float4*)(as_ + (size_t)s*HD + 4);
  float4 d0 = *(const float4*)(ad_ + (size_t)d*HD);
  float4 d1 = *(const float4*)(ad_ + (size_t)d*HD + 4);
  float4 w0, w1;
  w0.x = __expf(lrelu(s0.x + d0.x)); w0.y = __expf(lrelu(s0.y + d0.y));
  w0.z = __expf(lrelu(s0.z + d0.z)); w0.w = __expf(lrelu(s0.w + d0.w));
  w1.x = __expf(lrelu(s1.x + d1.x)); w1.y = __expf(lrelu(s1.y + d1.y));
  w1.z = __expf(lrelu(s1.z + d1.z)); w1.w = __expf(lrelu(s1.w + d1.w));
  *(float4*)(w_csr + (size_t)pos*HD)     = w0;
  *(float4*)(w_csr + (size_t)pos*HD + 4) = w1;
}

// ---------------- K4: weighted gather with precomputed weights ----------------
// 4 waves/block, one node per wave. Lane t: output dims 2t..2t+1, head hb=t>>3.
// Per 16-edge chunk: 16 csr loads (one line, broadcast) -> 16 h-gathers (the only
// random access left) || 16 w loads (sequential, broadcast within head group,
// independent of csr). No as_/lrelu/exp in the hot loop. csr/w loads are
// nontemporal to keep h resident in L2.
__global__ __launch_bounds__(256) void k_aggr(const float* __restrict__ h,
    const float* __restrict__ as_, const float* __restrict__ ad_,
    const int* __restrict__ row_ofs, const int* __restrict__ csr_src,
    const float* __restrict__ w_csr, const float* __restrict__ bias,
    float* __restrict__ out, int N)
{
  const int n = blockIdx.x*4 + (threadIdx.x >> 6);
  if (n >= N) return;
  const int t  = threadIdx.x & 63;
  const int hb = t >> 3;
  const int off = t*2;

  const float w_self = __expf(lrelu(as_[(size_t)n*HD + hb] + ad_[(size_t)n*HD + hb]));

  float sum = w_self;
  float2 hv = *(const float2*)(h + (size_t)n*DIM + off);
  float2 acc; acc.x = w_self*hv.x; acc.y = w_self*hv.y;

  const int ofs = row_ofs[n];
  const int deg = row_ofs[n+1] - ofs;

  for (int jb = 0; jb < deg; jb += 16){
    const int c = deg - jb;               // valid slots this chunk (>=1)
    int s[16];
    #pragma unroll
    for (int q = 0; q < 16; ++q){
      int sq = __builtin_nontemporal_load(csr_src + ofs + jb + q);  // padded: safe
      s[q] = (q < c) ? sq : n;
    }

    float2 hq[16];                         // the only random gathers
    #pragma unroll
    for (int q = 0; q < 16; ++q)
      hq[q] = *(const float2*)(h + (size_t)s[q]*DIM + off);

    float w[16];
    #pragma unroll
    for (int q = 0; q < 16; ++q){
      float wv = __builtin_nontemporal_load(w_csr + (size_t)(ofs+jb+q)*HD + hb);
      w[q] = (q < c) ? wv : 0.f;
    }

    #pragma unroll
    for (int q = 0; q < 16; ++q){
      sum   += w[q];
      acc.x += w[q]*hq[q].x;
      acc.y += w[q]*hq[q].y;
    }
  }

  const float2 bv = *(const float2*)(bias + off);
  const float inv = 1.0f / (sum + 1e-16f);
  float2 o;
  o.x = acc.x*inv + bv.x;
  o.y = acc.y*inv + bv.y;
  *(float2*)(out + (size_t)n*DIM + off) = o;
}

extern "C" void kernel_launch(void* const* d_in, const int* in_sizes, int n_in,
                              void* d_out, int out_size, void* d_ws, size_t ws_size,
                              hipStream_t stream)
{
  const float* x     = (const float*)d_in[0];
  const int*   ei    = (const int*)  d_in[1];
  const float* W     = (const float*)d_in[2];
  const float* a_src = (const float*)d_in[3];
  const float* a_dst = (const float*)d_in[4];
  const float* bias  = (const float*)d_in[5];
  float* out = (float*)d_out;

  const int N = in_sizes[0] / DIM;
  const int E = in_sizes[1] / 2;
  const int* src = ei;
  const int* dst = ei + E;

  char* w = (char*)d_ws;
  float* h     = (float*)w; w += (size_t)N*DIM*4;
  float* as_   = (float*)w; w += (size_t)N*HD*4;
  float* ad_   = (float*)w; w += (size_t)N*HD*4;
  float* w_csr = (float*)w; w += (size_t)(E+16)*HD*4;  // +16 pad for chunk over-read
  int* csr_src = (int*)w;   w += (size_t)(E+16)*4;     // +16 pad
  int* cnt     = (int*)w;   w += (size_t)N*4;
  int* wpos    = (int*)w;   w += (size_t)N*4;
  int* bsum    = (int*)w;   w += 256*4;
  int* row_ofs = (int*)w;   w += (size_t)(N+1)*4;

  const int chunk = (N + 255) / 256;   // 196 for N=50000 (must be <=256)

  hipLaunchKernelGGL(k_gemm,    dim3((N+63)/64),   dim3(256), 0, stream, x, W, a_src, a_dst, h, as_, ad_, N);
  hipMemsetAsync(cnt, 0, (size_t)N*4, stream);
  hipLaunchKernelGGL(k_count,   dim3((E+255)/256), dim3(256), 0, stream, dst, cnt, E);
  hipLaunchKernelGGL(k_scan1,   dim3(256),         dim3(256), 0, stream, cnt, bsum, chunk, N);
  hipLaunchKernelGGL(k_scan2,   dim3(1),           dim3(256), 0, stream, bsum, row_ofs, N);
  hipLaunchKernelGGL(k_scan3,   dim3(256),         dim3(256), 0, stream, cnt, bsum, row_ofs, wpos, chunk, N);
  hipLaunchKernelGGL(k_scatter, dim3((E+255)/256), dim3(256), 0, stream, src, dst, as_, ad_, wpos, csr_src, w_csr, E);
  hipLaunchKernelGGL(k_aggr,    dim3((N+3)/4),     dim3(256), 0, stream, h, as_, ad_, row_ofs, csr_src, w_csr, bias, out, N);
}

// Round 6
// 141.552 us; speedup vs baseline: 1.2186x; 1.2186x over previous
//
#include <hip/hip_runtime.h>
#include <hip/hip_fp16.h>

#define HD 8
#define CD 16
#define DIM 128
#define NEG_SLOPE 0.2f

static __device__ __forceinline__ float lrelu(float v){ return v > 0.f ? v : NEG_SLOPE*v; }

// ---------------- K1: h = x @ W (fp16 out), plus alpha_src/alpha_dst epilogue ----------------
__global__ __launch_bounds__(256) void k_gemm(const float* __restrict__ x,
    const float* __restrict__ W, const float* __restrict__ a_src_g, const float* __restrict__ a_dst_g,
    __half* __restrict__ hout, float* __restrict__ as_o, float* __restrict__ ad_o, int N)
{
  __shared__ float xs[64*DIM]; // 32 KB
  const int tid = threadIdx.x;
  const int c = tid & 31;
  const int r = tid >> 5;
  const long nbase = (long)blockIdx.x * 64;

  #pragma unroll
  for (int it = 0; it < 8; ++it){
    int lin = it*1024 + tid*4;
    long node = nbase + (lin >> 7);
    float4 v = make_float4(0.f,0.f,0.f,0.f);
    if (node < N) v = *(const float4*)(x + node*DIM + (lin & 127));
    *(float4*)(xs + lin) = v;
  }
  __syncthreads();

  float acc[8][4];
  #pragma unroll
  for (int i = 0; i < 8; ++i){ acc[i][0]=0.f; acc[i][1]=0.f; acc[i][2]=0.f; acc[i][3]=0.f; }

  for (int k = 0; k < DIM; k += 4){
    float4 w0 = *(const float4*)(W + (size_t)(k+0)*DIM + 4*c);
    float4 w1 = *(const float4*)(W + (size_t)(k+1)*DIM + 4*c);
    float4 w2 = *(const float4*)(W + (size_t)(k+2)*DIM + 4*c);
    float4 w3 = *(const float4*)(W + (size_t)(k+3)*DIM + 4*c);
    #pragma unroll
    for (int i = 0; i < 8; ++i){
      float4 xv = *(const float4*)(xs + (r*8+i)*DIM + k);
      acc[i][0] += xv.x*w0.x + xv.y*w1.x + xv.z*w2.x + xv.w*w3.x;
      acc[i][1] += xv.x*w0.y + xv.y*w1.y + xv.z*w2.y + xv.w*w3.y;
      acc[i][2] += xv.x*w0.z + xv.y*w1.z + xv.z*w2.z + xv.w*w3.z;
      acc[i][3] += xv.x*w0.w + xv.y*w1.w + xv.z*w2.w + xv.w*w3.w;
    }
  }

  float4 asv = *(const float4*)(a_src_g + 4*c);
  float4 adv = *(const float4*)(a_dst_g + 4*c);
  #pragma unroll
  for (int i = 0; i < 8; ++i){
    long node = nbase + r*8 + i;
    float ps = acc[i][0]*asv.x + acc[i][1]*asv.y + acc[i][2]*asv.z + acc[i][3]*asv.w;
    float pd = acc[i][0]*adv.x + acc[i][1]*adv.y + acc[i][2]*adv.z + acc[i][3]*adv.w;
    ps += __shfl_xor(ps, 1); ps += __shfl_xor(ps, 2);
    pd += __shfl_xor(pd, 1); pd += __shfl_xor(pd, 2);
    if (node < N){
      union { __half2 h2[2]; uint2 u; } pk;
      pk.h2[0] = __floats2half2_rn(acc[i][0], acc[i][1]);
      pk.h2[1] = __floats2half2_rn(acc[i][2], acc[i][3]);
      *(uint2*)(hout + node*DIM + 4*c) = pk.u;
      if ((c & 3) == 0){
        as_o[node*HD + (c>>2)] = ps;
        ad_o[node*HD + (c>>2)] = pd;
      }
    }
  }
}

// ---------------- CSR build ----------------
__global__ void k_count(const int* __restrict__ dst, int* __restrict__ cnt, int E){
  int e = blockIdx.x*256 + threadIdx.x;
  if (e < E) atomicAdd(&cnt[dst[e]], 1);
}

__global__ __launch_bounds__(256) void k_scan1(const int* __restrict__ cnt, int* __restrict__ bsum,
                                               int chunk, int N){
  __shared__ int tmp[256];
  int t = threadIdx.x;
  int base = blockIdx.x * chunk;
  int i = base + t;
  int v = (t < chunk && i < N) ? cnt[i] : 0;
  tmp[t] = v; __syncthreads();
  for (int off = 128; off > 0; off >>= 1){
    if (t < off) tmp[t] += tmp[t+off];
    __syncthreads();
  }
  if (t == 0) bsum[blockIdx.x] = tmp[0];
}

__global__ __launch_bounds__(256) void k_scan2(int* __restrict__ bsum, int* __restrict__ row_ofs, int N){
  __shared__ int tmp[256];
  int t = threadIdx.x;
  int v = bsum[t];
  tmp[t] = v; __syncthreads();
  for (int off = 1; off < 256; off <<= 1){
    int u = (t >= off) ? tmp[t-off] : 0;
    __syncthreads();
    tmp[t] += u;
    __syncthreads();
  }
  bsum[t] = tmp[t] - v;            // exclusive
  if (t == 255) row_ofs[N] = tmp[255];
}

__global__ __launch_bounds__(256) void k_scan3(const int* __restrict__ cnt, const int* __restrict__ bsum,
                                               int* __restrict__ row_ofs, int* __restrict__ wpos,
                                               int chunk, int N){
  __shared__ int tmp[256];
  int t = threadIdx.x;
  int base = blockIdx.x * chunk;
  int i = base + t;
  int v = (t < chunk && i < N) ? cnt[i] : 0;
  tmp[t] = v; __syncthreads();
  for (int off = 1; off < 256; off <<= 1){
    int u = (t >= off) ? tmp[t-off] : 0;
    __syncthreads();
    tmp[t] += u;
    __syncthreads();
  }
  int excl = tmp[t] - v;
  int bbase = bsum[blockIdx.x];
  if (t < chunk && i < N){
    row_ofs[i] = bbase + excl;
    wpos[i]    = bbase + excl;
  }
}

// scatter edges into CSR order; compute FINAL per-edge softmax weights (post-exp)
// for all 8 heads once per edge (valid because no max-shift is needed).
__global__ void k_scatter(const int* __restrict__ src, const int* __restrict__ dst,
                          const float* __restrict__ as_, const float* __restrict__ ad_,
                          int* __restrict__ wpos, int* __restrict__ csr_src,
                          float* __restrict__ w_csr, int E){
  int e = blockIdx.x*256 + threadIdx.x;
  if (e >= E) return;
  int s = src[e], d = dst[e];
  int pos = atomicAdd(&wpos[d], 1);
  csr_src[pos] = s;
  float4 s0 = *(const float4*)(as_ + (size_t)s*HD);
  float4 s1 = *(const float4*)(as_ + (size_t)s*HD + 4);
  float4 d0 = *(const float4*)(ad_ + (size_t)d*HD);
  float4 d1 = *(const float4*)(ad_ + (size_t)d*HD + 4);
  float4 w0, w1;
  w0.x = __expf(lrelu(s0.x + d0.x)); w0.y = __expf(lrelu(s0.y + d0.y));
  w0.z = __expf(lrelu(s0.z + d0.z)); w0.w = __expf(lrelu(s0.w + d0.w));
  w1.x = __expf(lrelu(s1.x + d1.x)); w1.y = __expf(lrelu(s1.y + d1.y));
  w1.z = __expf(lrelu(s1.z + d1.z)); w1.w = __expf(lrelu(s1.w + d1.w));
  *(float4*)(w_csr + (size_t)pos*HD)     = w0;
  *(float4*)(w_csr + (size_t)pos*HD + 4) = w1;
}

// ---------------- K4: weighted gather (fp16 h) with precomputed weights ----------------
// 4 waves/block, one node per wave. Lane t: output dims 2t..2t+1, head hb=t>>3.
// h is fp16: per-edge gather is 256 B/wave (2 cache lines), halving beyond-L2 traffic
// and halving hq register cost (1 VGPR per edge). Plain (cached) loads everywhere —
// the r5 nontemporal hints lengthened the csr critical path and regressed.
__global__ __launch_bounds__(256) void k_aggr(const __half* __restrict__ h,
    const float* __restrict__ as_, const float* __restrict__ ad_,
    const int* __restrict__ row_ofs, const int* __restrict__ csr_src,
    const float* __restrict__ w_csr, const float* __restrict__ bias,
    float* __restrict__ out, int N)
{
  const int n = blockIdx.x*4 + (threadIdx.x >> 6);
  if (n >= N) return;
  const int t  = threadIdx.x & 63;
  const int hb = t >> 3;
  const int off = t*2;

  const float w_self = __expf(lrelu(as_[(size_t)n*HD + hb] + ad_[(size_t)n*HD + hb]));

  float sum = w_self;
  float2 hv = __half22float2(*(const __half2*)(h + (size_t)n*DIM + off));
  float2 acc; acc.x = w_self*hv.x; acc.y = w_self*hv.y;

  const int ofs = row_ofs[n];
  const int deg = row_ofs[n+1] - ofs;

  for (int jb = 0; jb < deg; jb += 16){
    const int c = deg - jb;               // valid slots this chunk (>=1)
    int s[16];
    #pragma unroll
    for (int q = 0; q < 16; ++q){
      int sq = csr_src[ofs + jb + q];     // padded: safe to over-read
      s[q] = (q < c) ? sq : n;
    }

    __half2 hq[16];                        // 16 independent gathers, 1 VGPR each
    #pragma unroll
    for (int q = 0; q < 16; ++q)
      hq[q] = *(const __half2*)(h + (size_t)s[q]*DIM + off);

    float w[16];
    #pragma unroll
    for (int q = 0; q < 16; ++q){
      float wv = w_csr[(size_t)(ofs+jb+q)*HD + hb];   // padded: safe
      w[q] = (q < c) ? wv : 0.f;
    }

    #pragma unroll
    for (int q = 0; q < 16; ++q){
      float2 hf = __half22float2(hq[q]);
      sum   += w[q];
      acc.x += w[q]*hf.x;
      acc.y += w[q]*hf.y;
    }
  }

  const float2 bv = *(const float2*)(bias + off);
  const float inv = 1.0f / (sum + 1e-16f);
  float2 o;
  o.x = acc.x*inv + bv.x;
  o.y = acc.y*inv + bv.y;
  *(float2*)(out + (size_t)n*DIM + off) = o;
}

extern "C" void kernel_launch(void* const* d_in, const int* in_sizes, int n_in,
                              void* d_out, int out_size, void* d_ws, size_t ws_size,
                              hipStream_t stream)
{
  const float* x     = (const float*)d_in[0];
  const int*   ei    = (const int*)  d_in[1];
  const float* W     = (const float*)d_in[2];
  const float* a_src = (const float*)d_in[3];
  const float* a_dst = (const float*)d_in[4];
  const float* bias  = (const float*)d_in[5];
  float* out = (float*)d_out;

  const int N = in_sizes[0] / DIM;
  const int E = in_sizes[1] / 2;
  const int* src = ei;
  const int* dst = ei + E;

  char* w = (char*)d_ws;
  __half* h    = (__half*)w; w += (size_t)N*DIM*2;
  float* as_   = (float*)w; w += (size_t)N*HD*4;
  float* ad_   = (float*)w; w += (size_t)N*HD*4;
  float* w_csr = (float*)w; w += (size_t)(E+16)*HD*4;  // +16 pad for chunk over-read
  int* csr_src = (int*)w;   w += (size_t)(E+16)*4;     // +16 pad
  int* cnt     = (int*)w;   w += (size_t)N*4;
  int* wpos    = (int*)w;   w += (size_t)N*4;
  int* bsum    = (int*)w;   w += 256*4;
  int* row_ofs = (int*)w;   w += (size_t)(N+1)*4;

  const int chunk = (N + 255) / 256;   // 196 for N=50000 (must be <=256)

  hipLaunchKernelGGL(k_gemm,    dim3((N+63)/64),   dim3(256), 0, stream, x, W, a_src, a_dst, h, as_, ad_, N);
  hipMemsetAsync(cnt, 0, (size_t)N*4, stream);
  hipLaunchKernelGGL(k_count,   dim3((E+255)/256), dim3(256), 0, stream, dst, cnt, E);
  hipLaunchKernelGGL(k_scan1,   dim3(256),         dim3(256), 0, stream, cnt, bsum, chunk, N);
  hipLaunchKernelGGL(k_scan2,   dim3(1),           dim3(256), 0, stream, bsum, row_ofs, N);
  hipLaunchKernelGGL(k_scan3,   dim3(256),         dim3(256), 0, stream, cnt, bsum, row_ofs, wpos, chunk, N);
  hipLaunchKernelGGL(k_scatter, dim3((E+255)/256), dim3(256), 0, stream, src, dst, as_, ad_, wpos, csr_src, w_csr, E);
  hipLaunchKernelGGL(k_aggr,    dim3((N+3)/4),     dim3(256), 0, stream, h, as_, ad_, row_ofs, csr_src, w_csr, bias, out, N);
}